// Round 14
// baseline (102.953 us; speedup 1.0000x reference)
//
#include <hip/hip_runtime.h>
#include <stdint.h>

// Problem constants
#define S_LEN 2048
#define D_DIM 1024
#define NB 2
#define NH 16
#define NE 64
#define N_COLS (3 * NH * NE)  // 3072 (Q | K | V column blocks)
#define K_DIM D_DIM           // 1024

typedef unsigned short u16;
typedef unsigned int u32;
typedef u16 u16x8 __attribute__((ext_vector_type(8)));
typedef __bf16 bf16x8 __attribute__((ext_vector_type(8)));
typedef __bf16 bf16x4 __attribute__((ext_vector_type(4)));
typedef float f32x4 __attribute__((ext_vector_type(4)));

__device__ __forceinline__ u16 f2b(float f) {
  u32 u = __builtin_bit_cast(u32, f);
  return (u16)((u + 0x7FFFu + ((u >> 16) & 1u)) >> 16);  // RNE
}

__device__ __forceinline__ void gload_lds16(const void* g, void* l) {
  __builtin_amdgcn_global_load_lds(
      (const __attribute__((address_space(1))) u32*)g,
      (__attribute__((address_space(3))) u32*)l, 16, 0, 0);
}

// ---------- merged prep: blocks [0,2048) convert x; [2048,2816) transpose W ----------
__global__ __launch_bounds__(256) void k_prep(const float* __restrict__ x,
                                              const float* __restrict__ Wq,
                                              const float* __restrict__ Wk,
                                              const float* __restrict__ Wv,
                                              u16* __restrict__ xb,
                                              u16* __restrict__ Wt) {
  __shared__ u16 tile[64][65];
  int bid = blockIdx.x;
  int t = threadIdx.x;
  if (bid < 2048) {
    size_t i = (size_t)bid * 256 + t;
    const float4* xf = (const float4*)x;
    float4 a = xf[2 * i], c = xf[2 * i + 1];
    u16x8 o;
    o[0] = f2b(a.x); o[1] = f2b(a.y); o[2] = f2b(a.z); o[3] = f2b(a.w);
    o[4] = f2b(c.x); o[5] = f2b(c.y); o[6] = f2b(c.z); o[7] = f2b(c.w);
    *(u16x8*)(xb + 8 * i) = o;
  } else {
    int wbid = bid - 2048;             // proj*256 + h*16 + kb
    int kb = wbid & 15;
    int h = (wbid >> 4) & 15;
    int proj = wbid >> 8;
    const float* W = (proj == 0) ? Wq : ((proj == 1) ? Wk : Wv);
    int k0 = kb * 64;
    int e = t & 63, kr = t >> 6;
    const float* src = W + ((size_t)h * D_DIM + k0 + kr * 16) * NE + e;
#pragma unroll
    for (int j = 0; j < 16; ++j) tile[kr * 16 + j][e] = f2b(src[(size_t)j * NE]);
    __syncthreads();
    int e2 = t >> 2, kc = (t & 3) * 16;
    u16x8 o0, o1;
#pragma unroll
    for (int j = 0; j < 8; ++j) { o0[j] = tile[kc + j][e2]; o1[j] = tile[kc + 8 + j][e2]; }
    size_t n = (size_t)proj * 1024 + h * 64 + e2;
    u16* dst = Wt + n * K_DIM + k0 + kc;
    *(u16x8*)dst = o0;
    *(u16x8*)(dst + 8) = o1;
  }
}

// ------------- GEMM: qkv[4096,3072] = xb[4096,1024] @ Wt[3072,1024]^T -------------
__global__ __launch_bounds__(256) void k_gemm(const u16* __restrict__ A,
                                              const u16* __restrict__ Bt,
                                              u16* __restrict__ C) {
  __shared__ __align__(16) u16 As[128 * 64];
  __shared__ __align__(16) u16 Bs[128 * 64];
  int t = threadIdx.x;
  int lane = t & 63, w = t >> 6;
  int wr = (w >> 1) * 64, wc = (w & 1) * 64;
  int bid = blockIdx.x;
  int xcd = bid & 7, r0 = bid >> 3;          // r0 in [0,96)
  int m0 = (r0 / 3) * 128;
  int n0 = (xcd * 3 + (r0 % 3)) * 128;
  float qscale = ((n0 + wc) < 1024) ? 0.18033688f : 1.0f;  // 0.125*log2e
  f32x4 acc[4][4];
#pragma unroll
  for (int m = 0; m < 4; m++)
#pragma unroll
    for (int n = 0; n < 4; n++)
#pragma unroll
      for (int j = 0; j < 4; j++) acc[m][n][j] = 0.f;

  for (int k0 = 0; k0 < K_DIM; k0 += 64) {
#pragma unroll
    for (int i = 0; i < 4; ++i) {
      int ci = i * 256 + t;
      int row = ci >> 3, c = ci & 7;
      int cs = c ^ (row & 7);
      gload_lds16(A + (size_t)(m0 + row) * K_DIM + k0 + cs * 8,
                  (char*)As + (size_t)(i * 256 + w * 64) * 16);
      gload_lds16(Bt + (size_t)(n0 + row) * K_DIM + k0 + cs * 8,
                  (char*)Bs + (size_t)(i * 256 + w * 64) * 16);
    }
    __syncthreads();
#pragma unroll
    for (int ks = 0; ks < 2; ++ks) {
      int kc = ks * 4 + (lane >> 4);
      bf16x8 af[4], bfr[4];
#pragma unroll
      for (int m = 0; m < 4; m++) {
        int r = wr + m * 16 + (lane & 15);
        af[m] = *(const bf16x8*)&As[r * 64 + ((kc ^ (r & 7)) * 8)];
      }
#pragma unroll
      for (int n = 0; n < 4; n++) {
        int r = wc + n * 16 + (lane & 15);
        bfr[n] = *(const bf16x8*)&Bs[r * 64 + ((kc ^ (r & 7)) * 8)];
      }
#pragma unroll
      for (int m = 0; m < 4; m++)
#pragma unroll
        for (int n = 0; n < 4; n++)
          acc[m][n] = __builtin_amdgcn_mfma_f32_16x16x32_bf16(af[m], bfr[n], acc[m][n], 0, 0, 0);
    }
    __syncthreads();
  }
#pragma unroll
  for (int m = 0; m < 4; m++) {
#pragma unroll
    for (int r = 0; r < 4; r++) {
      int row = m0 + wr + m * 16 + (lane >> 4) * 4 + r;
#pragma unroll
      for (int n = 0; n < 4; n++) {
        int col = n0 + wc + n * 16 + (lane & 15);
        C[(size_t)row * N_COLS + col] = f2b(acc[m][n][r] * qscale);
      }
    }
  }
}

// ---- attention helpers (256-thread block) ----
__device__ __forceinline__ void stage_k(const u16* kb_, u16* kdst, int kv0, int t, int w) {
#pragma unroll
  for (int i = 0; i < 2; ++i) {
    int ci = i * 256 + t;
    int row = ci >> 3, c = ci & 7;
    int cs = c ^ (row & 7);
    gload_lds16(kb_ + (size_t)(kv0 + row) * N_COLS + cs * 8,
                (char*)kdst + (size_t)(i * 256 + w * 64) * 16);  // wave-uniform base
  }
}

// V write: thread covers kv pair vp = t>>3, e-chunk vec = t&7.
// Vt element (e,kv) at byte e*128 + slot*16 + (kv&7)*2, slot=(kv>>3)^(e&7)^(e>>3).
__device__ __forceinline__ void vwrite(u16* vt, u16x8 va, u16x8 vb2, int vp, int vec) {
#pragma unroll
  for (int j = 0; j < 8; ++j) {
    int e = vec * 8 + j;
    int slot = (vp >> 2) ^ (e & 7) ^ (e >> 3);
    *(u32*)((char*)vt + e * 128 + slot * 16 + (vp & 3) * 4) =
        (u32)va[j] | ((u32)vb2[j] << 16);
  }
}

// ------- flash attention, causal, swapped-QK^T register-P, capacity-exact balance -------
// No-max softmax => partials over disjoint kv ranges combine by ADDITION (2 fixed
// addends -> deterministic). Grid 1024 = 4 blocks/CU, ALL resident (r13 lesson:
// grid must not exceed residency). Per bh (32 blocks): A-block p (16): first 17
// kv-tiles of qt_hi=31-p (p=15: all of qt16 -> direct); B-block p (16): remaining
// 15-p tiles of qt_hi (incl. diagonal) then ALL of qt_lo=p (p+1 tiles) = 16 steps,
// switching Q-context mid-block (both qf sets preloaded; ctx0 flush -> raw out+l1).
// Every block 16-17 steps (was 1-32). k_fix combines 480 split tiles.
__global__ __launch_bounds__(256) void k_attn(const u16* __restrict__ qkv,
                                              float* __restrict__ out,
                                              float* __restrict__ O0,
                                              float* __restrict__ l0,
                                              float* __restrict__ l1) {
  __shared__ __align__(16) u16 Ks[2][64 * 64];
  __shared__ __align__(16) u16 Vt[2][64 * 64];
  int t = threadIdx.x;
  int lane = t & 63, w = t >> 6;
  int hi = lane >> 4, l15 = lane & 15;
  int bid = blockIdx.x;                 // 0..1023
  int x = bid & 7, g = bid >> 3;
  int bh = x * 4 + (g & 3);             // 4 heads' K/V (2 MB) per XCD L2
  int u = g >> 2;                       // 0..31
  bool isA = (u < 16);
  int p = isA ? u : u - 16;
  int qt0 = 31 - p;                     // ctx0 q-tile
  int qt1 = p;                          // ctx1 q-tile (B only)
  int c0len = isA ? 17 : (15 - p);      // entries in ctx0
  int n_entries = isA ? 17 : 16;
  int base0 = isA ? 0 : 17;             // ctx0 kv-tile start
  int b = bh >> 4, h = bh & 15;
  const u16* qb_ = qkv + (size_t)b * S_LEN * N_COLS + h * NE;
  const u16* kb_ = qb_ + 1024;
  const u16* vb_ = qb_ + 2048;
  int vp = t >> 3, vec = t & 7;

  int wq0 = qt0 * 64 + w * 16;          // ctx0 wave q base
  int wq1 = qt1 * 64 + w * 16;          // ctx1 wave q base
  int myq0 = wq0 + l15, myq1 = wq1 + l15;

  bf16x8 qf0[2], qf1[2];
#pragma unroll
  for (int ks = 0; ks < 2; ks++)
    qf0[ks] = *(const bf16x8*)(qb_ + (size_t)(wq0 + l15) * N_COLS + ks * 32 + hi * 8);
  if (!isA) {
#pragma unroll
    for (int ks = 0; ks < 2; ks++)
      qf1[ks] = *(const bf16x8*)(qb_ + (size_t)(wq1 + l15) * N_COLS + ks * 32 + hi * 8);
  }

  f32x4 o[4];
#pragma unroll
  for (int i = 0; i < 4; i++)
#pragma unroll
    for (int j2 = 0; j2 < 4; j2++) o[i][j2] = 0.f;
  float lsum = 0.f;

  // prologue: stage entry 0
  int ti0 = (c0len > 0) ? base0 : 0;
  stage_k(kb_, Ks[0], ti0 * 64, t, w);
  {
    const u16* vs = vb_ + (size_t)(ti0 * 64 + 2 * vp) * N_COLS + vec * 8;
    u16x8 va = *(const u16x8*)vs;
    u16x8 vb2 = *(const u16x8*)(vs + N_COLS);
    vwrite(Vt[0], va, vb2, vp, vec);
  }
  __syncthreads();

  int cur = 0;

#define ATTN_STEP(TI, QF, CQ, MYQ)                                              \
  {                                                                             \
    int kv0 = (TI) * 64;                                                        \
    bool pf = (j + 1 < n_entries);                                              \
    u16x8 va, vb2;                                                              \
    if (pf) {                                                                   \
      int tin = (j + 1 < c0len) ? (base0 + j + 1) : (j + 1 - c0len);            \
      const u16* vs = vb_ + (size_t)(tin * 64 + 2 * vp) * N_COLS + vec * 8;     \
      va = *(const u16x8*)vs;                                                   \
      vb2 = *(const u16x8*)(vs + N_COLS);                                       \
      stage_k(kb_, Ks[cur ^ 1], tin * 64, t, w);                                \
    }                                                                           \
    f32x4 s[4];                                                                 \
    _Pragma("unroll") for (int f = 0; f < 4; f++)                               \
        _Pragma("unroll") for (int j2 = 0; j2 < 4; j2++) s[f][j2] = 0.f;        \
    __builtin_amdgcn_s_setprio(1);                                              \
    _Pragma("unroll") for (int ks = 0; ks < 2; ks++) {                          \
      int kc = ks * 4 + hi;                                                     \
      _Pragma("unroll") for (int f = 0; f < 4; f++) {                           \
        int r = f * 16 + l15;                                                   \
        bf16x8 kf = *(const bf16x8*)&Ks[cur][r * 64 + ((kc ^ (r & 7)) * 8)];    \
        s[f] = __builtin_amdgcn_mfma_f32_16x16x32_bf16(kf, QF[ks], s[f], 0, 0, 0); \
      }                                                                         \
    }                                                                           \
    __builtin_amdgcn_s_setprio(0);                                              \
    bool diag = ((TI) == (CQ));                                                 \
    _Pragma("unroll") for (int f = 0; f < 4; f++) {                             \
      float pr[4];                                                              \
      _Pragma("unroll") for (int r = 0; r < 4; r++) {                           \
        float pp = __builtin_amdgcn_exp2f(s[f][r]);                             \
        if (diag) {                                                             \
          int kv = kv0 + f * 16 + 4 * hi + r;                                   \
          pp = (kv <= (MYQ)) ? pp : 0.f;                                        \
        }                                                                       \
        s[f][r] = pp;                                                           \
        pr[r] = pp;                                                             \
      }                                                                         \
      lsum += (pr[0] + pr[1]) + (pr[2] + pr[3]);                                \
    }                                                                           \
    if (pf) vwrite(Vt[cur ^ 1], va, vb2, vp, vec);                              \
    __builtin_amdgcn_s_setprio(1);                                              \
    _Pragma("unroll") for (int ks = 0; ks < 2; ks++) {                          \
      bf16x8 pa;                                                                \
      _Pragma("unroll") for (int j2 = 0; j2 < 4; j2++) {                        \
        pa[j2] = (__bf16)s[2 * ks][j2];                                         \
        pa[4 + j2] = (__bf16)s[2 * ks + 1][j2];                                 \
      }                                                                         \
      int kvo1 = 32 * ks + 4 * hi;                                              \
      int kvo2 = kvo1 + 16;                                                     \
      _Pragma("unroll") for (int ef = 0; ef < 4; ef++) {                        \
        int e = ef * 16 + l15;                                                  \
        int sw = (e & 7) ^ (e >> 3);                                            \
        int a1 = e * 128 + (((kvo1 >> 3) ^ sw) * 16) + (kvo1 & 7) * 2;          \
        int a2 = e * 128 + (((kvo2 >> 3) ^ sw) * 16) + (kvo2 & 7) * 2;          \
        bf16x4 vlo = *(const bf16x4*)((const char*)Vt[cur] + a1);               \
        bf16x4 vhi2 = *(const bf16x4*)((const char*)Vt[cur] + a2);              \
        bf16x8 vbf;                                                             \
        _Pragma("unroll") for (int j2 = 0; j2 < 4; j2++) {                      \
          vbf[j2] = vlo[j2];                                                    \
          vbf[4 + j2] = vhi2[j2];                                               \
        }                                                                       \
        o[ef] = __builtin_amdgcn_mfma_f32_16x16x32_bf16(pa, vbf, o[ef], 0, 0, 0); \
      }                                                                         \
    }                                                                           \
    __builtin_amdgcn_s_setprio(0);                                              \
    __syncthreads();                                                            \
    cur ^= 1;                                                                   \
  }

  int j = 0;
  for (; j < c0len; ++j) ATTN_STEP(base0 + j, qf0, qt0, myq0);

  if (!isA && c0len > 0) {
    // flush ctx0: raw partial of qt0 -> out rows + l1; reset accumulators
    float ls = lsum;
    ls += __shfl_xor(ls, 16);
    ls += __shfl_xor(ls, 32);
    int sp = bh * 15 + (qt0 - 17);
#pragma unroll
    for (int r = 0; r < 4; r++) {
      int q = wq0 + 4 * hi + r;
#pragma unroll
      for (int ef = 0; ef < 4; ef++) {
        int col = h * NE + ef * 16 + l15;
        out[((size_t)b * S_LEN + q) * (NH * NE) + col] = o[ef][r];
      }
    }
    if (lane < 16) l1[sp * 64 + w * 16 + l15] = ls;
#pragma unroll
    for (int i = 0; i < 4; i++)
#pragma unroll
      for (int j2 = 0; j2 < 4; j2++) o[i][j2] = 0.f;
    lsum = 0.f;
  }

  for (; j < n_entries; ++j) ATTN_STEP(j - c0len, qf1, qt1, myq1);
#undef ATTN_STEP

  // final context epilogue
  lsum += __shfl_xor(lsum, 16);
  lsum += __shfl_xor(lsum, 32);
  if (isA) {
    if (p == 15) {
      // complete tile (qt16): normalize direct
#pragma unroll
      for (int r = 0; r < 4; r++) {
        float l = __shfl(lsum, 4 * hi + r);
        float inv = 1.0f / l;
        int q = wq0 + 4 * hi + r;
#pragma unroll
        for (int ef = 0; ef < 4; ef++) {
          int col = h * NE + ef * 16 + l15;
          out[((size_t)b * S_LEN + q) * (NH * NE) + col] = o[ef][r] * inv;
        }
      }
    } else {
      // partial of qt0 -> O0, l0
      int sp = bh * 15 + (qt0 - 17);
#pragma unroll
      for (int r = 0; r < 4; r++) {
        int row = w * 16 + 4 * hi + r;
#pragma unroll
        for (int ef = 0; ef < 4; ef++)
          O0[(size_t)sp * 4096 + row * 64 + ef * 16 + l15] = o[ef][r];
      }
      if (lane < 16) l0[sp * 64 + w * 16 + l15] = lsum;
    }
  } else {
    // ctx1 complete (qt1): normalize direct
#pragma unroll
    for (int r = 0; r < 4; r++) {
      float l = __shfl(lsum, 4 * hi + r);
      float inv = 1.0f / l;
      int q = wq1 + 4 * hi + r;
#pragma unroll
      for (int ef = 0; ef < 4; ef++) {
        int col = h * NE + ef * 16 + l15;
        out[((size_t)b * S_LEN + q) * (NH * NE) + col] = o[ef][r] * inv;
      }
    }
  }
}

// ---- combine split partials: out = (out + O0) / (l0 + l1), 480 split tiles ----
__global__ __launch_bounds__(256) void k_fix(float* __restrict__ out,
                                             const float* __restrict__ O0,
                                             const float* __restrict__ l0,
                                             const float* __restrict__ l1) {
  int f = (blockIdx.x * 256 + threadIdx.x) * 4;   // over 480*4096 elems
  int sp = f >> 12;
  int row = (f >> 6) & 63;
  int e0 = f & 63;
  int bh = sp / 15, qt = 17 + (sp % 15);
  int b = bh >> 4, h = bh & 15;
  int q = qt * 64 + row;
  float inv = 1.0f / (l0[sp * 64 + row] + l1[sp * 64 + row]);
  float4 p0 = *(const float4*)&O0[(size_t)sp * 4096 + row * 64 + e0];
  size_t oi = ((size_t)b * S_LEN + q) * (NH * NE) + h * NE + e0;
  float4 cu = *(float4*)&out[oi];
  float4 res;
  res.x = (cu.x + p0.x) * inv;
  res.y = (cu.y + p0.y) * inv;
  res.z = (cu.z + p0.z) * inv;
  res.w = (cu.w + p0.w) * inv;
  *(float4*)&out[oi] = res;
}

extern "C" void kernel_launch(void* const* d_in, const int* in_sizes, int n_in,
                              void* d_out, int out_size, void* d_ws, size_t ws_size,
                              hipStream_t stream) {
  const float* x = (const float*)d_in[0];
  const float* Wq = (const float*)d_in[1];
  const float* Wk = (const float*)d_in[2];
  const float* Wv = (const float*)d_in[3];
  float* out = (float*)d_out;

  char* ws = (char*)d_ws;
  u16* xb = (u16*)ws;                          // 4096*1024*2  = 8 MB
  u16* Wt = (u16*)(ws + (8u << 20));           // 3072*1024*2  = 6 MB
  u16* qkv = (u16*)(ws + (14u << 20));         // 4096*3072*2  = 24 MB
  // attn partials alias the xb/Wt region (dead after k_gemm):
  float* O0 = (float*)ws;                      // 480*4096*4   = 7.9 MB
  float* l0 = (float*)(ws + (8u << 20));       // 123 KB
  float* l1 = (float*)(ws + (8u << 20) + (256u << 10));  // 123 KB

  k_prep<<<dim3(2816), dim3(256), 0, stream>>>(x, Wq, Wk, Wv, xb, Wt);
  k_gemm<<<dim3(768), dim3(256), 0, stream>>>(xb, Wt, qkv);
  k_attn<<<dim3(1024), dim3(256), 0, stream>>>(qkv, out, O0, l0, l1);
  k_fix<<<dim3(1920), dim3(256), 0, stream>>>(out, O0, l0, l1);
}